// Round 2
// baseline (997.097 us; speedup 1.0000x reference)
//
#include <hip/hip_runtime.h>

// GCN forward: deg/dinv -> CSR build (per call) -> 3x [GEMM(+fused BN/ReLU of prev layer)
// -> CSR SpMM aggregate (no atomics) -> BN stats] -> fused BN/ReLU+pool+MLP tail.
// All scratch carved from d_ws; only degi histogram + bnstats are memset per call.

constexpr int F = 128;
constexpr float BN_EPS = 1e-5f;

// ---------------- degree histogram over dst ----------------
__global__ void hist_k(const int* __restrict__ dst, int* __restrict__ degi, int E) {
  int stride = gridDim.x * blockDim.x;
  for (int e = blockIdx.x * blockDim.x + threadIdx.x; e < E; e += stride)
    atomicAdd(&degi[dst[e]], 1);
}

// ---------------- scan stage A: per-chunk(1024) sums + dinv ----------------
__global__ __launch_bounds__(256) void scanA_k(const int* __restrict__ degi, int* __restrict__ bsums,
                                               float* __restrict__ dinv, int n) {
  __shared__ int red[256];
  int tid = threadIdx.x;
  int base = blockIdx.x * 1024 + tid * 4;
  int4 v = *(const int4*)(degi + base);  // padded region is zeroed
  if (base + 0 < n) dinv[base + 0] = rsqrtf((float)v.x + 1.0f);
  if (base + 1 < n) dinv[base + 1] = rsqrtf((float)v.y + 1.0f);
  if (base + 2 < n) dinv[base + 2] = rsqrtf((float)v.z + 1.0f);
  if (base + 3 < n) dinv[base + 3] = rsqrtf((float)v.w + 1.0f);
  red[tid] = v.x + v.y + v.z + v.w;
  __syncthreads();
  for (int off = 128; off > 0; off >>= 1) {
    if (tid < off) red[tid] += red[tid + off];
    __syncthreads();
  }
  if (tid == 0) bsums[blockIdx.x] = red[0];
}

// ---------------- scan stage B: exclusive scan of block sums (1 block) ----------------
__global__ void scanB_k(int* __restrict__ bsums, int nb, int* __restrict__ rowptr, int N) {
  __shared__ int sh[1024];
  int tid = threadIdx.x;
  for (int i = tid; i < nb; i += blockDim.x) sh[i] = bsums[i];
  __syncthreads();
  if (tid == 0) {
    int run = 0;
    for (int i = 0; i < nb; ++i) { int t = sh[i]; sh[i] = run; run += t; }
    rowptr[N] = run;  // == E
  }
  __syncthreads();
  for (int i = tid; i < nb; i += blockDim.x) bsums[i] = sh[i];
}

// ---------------- scan stage C: full exclusive scan -> rowptr & cursor ----------------
__global__ __launch_bounds__(256) void scanC_k(const int* __restrict__ degi, const int* __restrict__ bsums,
                                               int* __restrict__ rowptr, int* __restrict__ cursor, int n) {
  __shared__ int ts[256];
  int tid = threadIdx.x;
  int base = blockIdx.x * 1024 + tid * 4;
  int4 v = *(const int4*)(degi + base);
  int e0 = v.x, e1 = v.y, e2 = v.z, e3 = v.w;
  int tot = e0 + e1 + e2 + e3;
  ts[tid] = tot;
  __syncthreads();
  for (int off = 1; off < 256; off <<= 1) {
    int add = (tid >= off) ? ts[tid - off] : 0;
    __syncthreads();
    ts[tid] += add;
    __syncthreads();
  }
  int excl = ts[tid] - tot + bsums[blockIdx.x];
  int p0 = excl, p1 = p0 + e0, p2 = p1 + e1, p3 = p2 + e2;
  if (base + 0 < n) { rowptr[base + 0] = p0; cursor[base + 0] = p0; }
  if (base + 1 < n) { rowptr[base + 1] = p1; cursor[base + 1] = p1; }
  if (base + 2 < n) { rowptr[base + 2] = p2; cursor[base + 2] = p2; }
  if (base + 3 < n) { rowptr[base + 3] = p3; cursor[base + 3] = p3; }
}

// ---------------- CSR scatter: cols sorted by dst ----------------
__global__ void scatter_k(const int* __restrict__ src, const int* __restrict__ dst,
                          int* __restrict__ cursor, int* __restrict__ cols, int E) {
  int stride = gridDim.x * blockDim.x;
  for (int e = blockIdx.x * blockDim.x + threadIdx.x; e < E; e += stride) {
    int d = dst[e];
    int pos = atomicAdd(&cursor[d], 1);
    cols[pos] = src[e];
  }
}

// ---------------- fp32 GEMM: C[n,128] = bnrelu(A)[n,128] @ W[128,128] ----------------
// Tile 64 rows x 64 cols, K=128 fully resident. A tile stored [k][row^swz] so that
// both transpose-staging stores and inner-loop float2 reads are <=2-way bank conflicts.
__global__ __launch_bounds__(256) void gemm_k(const float* __restrict__ A, const float* __restrict__ W,
                                              float* __restrict__ C, int n,
                                              const float* __restrict__ stats,
                                              const float* __restrict__ gamma,
                                              const float* __restrict__ beta,
                                              float inv_n) {
  __shared__ float Al[F][64];  // [k][row ^ f(k)]
  __shared__ float Wl[F][64];  // [k][col]
  const int tid = threadIdx.x;
  const int r0 = blockIdx.x * 64;
  const int c0 = blockIdx.y * 64;

  // BN scale/shift for this thread's fixed k-range (features k4..k4+3)
  const int k4 = (tid & 31) * 4;
  float sc0 = 1.f, sc1 = 1.f, sc2 = 1.f, sc3 = 1.f;
  float sh0 = 0.f, sh1 = 0.f, sh2 = 0.f, sh3 = 0.f;
  if (stats) {
    float4 s  = *(const float4*)(stats + k4);
    float4 sq = *(const float4*)(stats + F + k4);
    float4 ga = *(const float4*)(gamma + k4);
    float4 be = *(const float4*)(beta + k4);
    float mu, var, rs;
    mu = s.x * inv_n; var = sq.x * inv_n - mu * mu; rs = rsqrtf(var + BN_EPS);
    sc0 = ga.x * rs; sh0 = be.x - mu * sc0;
    mu = s.y * inv_n; var = sq.y * inv_n - mu * mu; rs = rsqrtf(var + BN_EPS);
    sc1 = ga.y * rs; sh1 = be.y - mu * sc1;
    mu = s.z * inv_n; var = sq.z * inv_n - mu * mu; rs = rsqrtf(var + BN_EPS);
    sc2 = ga.z * rs; sh2 = be.z - mu * sc2;
    mu = s.w * inv_n; var = sq.w * inv_n - mu * mu; rs = rsqrtf(var + BN_EPS);
    sc3 = ga.w * rs; sh3 = be.w - mu * sc3;
  }

  const int fsw = 2 * (tid & 31);  // == (2*(k>>2))&63 for k in [k4,k4+4)
#pragma unroll
  for (int i = 0; i < 8; ++i) {
    int idx = i * 256 + tid;
    int row = idx >> 5;          // 32 float4 per row
    int r = r0 + row;
    float4 v = {0.f, 0.f, 0.f, 0.f};
    if (r < n) v = *(const float4*)(A + (size_t)r * F + k4);
    if (stats) {
      v.x = fmaxf(v.x * sc0 + sh0, 0.f);
      v.y = fmaxf(v.y * sc1 + sh1, 0.f);
      v.z = fmaxf(v.z * sc2 + sh2, 0.f);
      v.w = fmaxf(v.w * sc3 + sh3, 0.f);
    }
    int rsw = row ^ fsw;
    Al[k4 + 0][rsw] = v.x;
    Al[k4 + 1][rsw] = v.y;
    Al[k4 + 2][rsw] = v.z;
    Al[k4 + 3][rsw] = v.w;
  }
#pragma unroll
  for (int i = 0; i < 8; ++i) {
    int idx = i * 256 + tid;
    int k = idx >> 4;            // 16 float4 per 64-col row
    int c4 = (idx & 15) * 4;
    *(float4*)&Wl[k][c4] = *(const float4*)(W + (size_t)k * F + c0 + c4);
  }
  __syncthreads();

  const int rg = tid >> 3;  // rows 2rg, 2rg+1
  const int cg = tid & 7;   // cols 8cg..8cg+7
  float acc0[8] = {0, 0, 0, 0, 0, 0, 0, 0};
  float acc1[8] = {0, 0, 0, 0, 0, 0, 0, 0};
#pragma unroll 8
  for (int k = 0; k < F; ++k) {
    int f = (2 * (k >> 2)) & 63;
    float2 a = *(const float2*)&Al[k][(2 * rg) ^ f];
    float4 w0 = *(const float4*)&Wl[k][cg * 8];
    float4 w1 = *(const float4*)&Wl[k][cg * 8 + 4];
    acc0[0] = fmaf(a.x, w0.x, acc0[0]); acc1[0] = fmaf(a.y, w0.x, acc1[0]);
    acc0[1] = fmaf(a.x, w0.y, acc0[1]); acc1[1] = fmaf(a.y, w0.y, acc1[1]);
    acc0[2] = fmaf(a.x, w0.z, acc0[2]); acc1[2] = fmaf(a.y, w0.z, acc1[2]);
    acc0[3] = fmaf(a.x, w0.w, acc0[3]); acc1[3] = fmaf(a.y, w0.w, acc1[3]);
    acc0[4] = fmaf(a.x, w1.x, acc0[4]); acc1[4] = fmaf(a.y, w1.x, acc1[4]);
    acc0[5] = fmaf(a.x, w1.y, acc0[5]); acc1[5] = fmaf(a.y, w1.y, acc1[5]);
    acc0[6] = fmaf(a.x, w1.z, acc0[6]); acc1[6] = fmaf(a.y, w1.z, acc1[6]);
    acc0[7] = fmaf(a.x, w1.w, acc0[7]); acc1[7] = fmaf(a.y, w1.w, acc1[7]);
  }
  int r = r0 + 2 * rg;
  size_t cbase = (size_t)r * F + c0 + cg * 8;
  if (r < n) {
    float4 o0 = {acc0[0], acc0[1], acc0[2], acc0[3]};
    float4 o1 = {acc0[4], acc0[5], acc0[6], acc0[7]};
    *(float4*)(C + cbase) = o0;
    *(float4*)(C + cbase + 4) = o1;
  }
  if (r + 1 < n) {
    float4 o0 = {acc1[0], acc1[1], acc1[2], acc1[3]};
    float4 o1 = {acc1[4], acc1[5], acc1[6], acc1[7]};
    *(float4*)(C + cbase + F) = o0;
    *(float4*)(C + cbase + F + 4) = o1;
  }
}

// ---------------- CSR SpMM aggregate: one wave per dst row, no atomics ----------------
// out[d] = dinv[d] * ( sum_e dinv[src_e]*hw[src_e] + dinv[d]*hw[d] ) + bias
__global__ __launch_bounds__(256) void spmm_k(const float* __restrict__ hw, const int* __restrict__ rowptr,
                                              const int* __restrict__ cols, const float* __restrict__ dinv,
                                              const float* __restrict__ bias, float* __restrict__ out, int n) {
  int wid = (blockIdx.x * 256 + threadIdx.x) >> 6;
  int lane = threadIdx.x & 63;
  if (wid >= n) return;
  const float2* hw2 = (const float2*)hw;
  float di = dinv[wid];
  float2 v = hw2[(size_t)wid * 64 + lane];
  float ax = di * v.x, ay = di * v.y;  // self-loop term (di factored outside)
  int j = rowptr[wid], e = rowptr[wid + 1];
  for (; j + 4 <= e; j += 4) {
    int c0 = cols[j], c1 = cols[j + 1], c2 = cols[j + 2], c3 = cols[j + 3];
    float d0 = dinv[c0], d1 = dinv[c1], d2 = dinv[c2], d3 = dinv[c3];
    float2 v0 = hw2[(size_t)c0 * 64 + lane];
    float2 v1 = hw2[(size_t)c1 * 64 + lane];
    float2 v2 = hw2[(size_t)c2 * 64 + lane];
    float2 v3 = hw2[(size_t)c3 * 64 + lane];
    ax = fmaf(d0, v0.x, ax); ay = fmaf(d0, v0.y, ay);
    ax = fmaf(d1, v1.x, ax); ay = fmaf(d1, v1.y, ay);
    ax = fmaf(d2, v2.x, ax); ay = fmaf(d2, v2.y, ay);
    ax = fmaf(d3, v3.x, ax); ay = fmaf(d3, v3.y, ay);
  }
  for (; j < e; ++j) {
    int c = cols[j];
    float dd = dinv[c];
    float2 vv = hw2[(size_t)c * 64 + lane];
    ax = fmaf(dd, vv.x, ax); ay = fmaf(dd, vv.y, ay);
  }
  float2 b = ((const float2*)bias)[lane];
  float2 o;
  o.x = fmaf(di, ax, b.x);
  o.y = fmaf(di, ay, b.y);
  ((float2*)out)[(size_t)wid * 64 + lane] = o;
}

// ---------------- BN statistics: sum & sumsq per feature ----------------
__global__ __launch_bounds__(256) void stats_k(const float* __restrict__ h, float* __restrict__ stats, int n) {
  __shared__ float s1[256], s2[256];
  int tid = threadIdx.x;
  int c = tid & 127, half = tid >> 7;
  float a = 0.f, b = 0.f;
  for (int r = blockIdx.x * 2 + half; r < n; r += gridDim.x * 2) {
    float v = h[(size_t)r * F + c];
    a += v;
    b += v * v;
  }
  s1[tid] = a; s2[tid] = b;
  __syncthreads();
  if (tid < 128) {
    atomicAdd(&stats[c], s1[tid] + s1[tid + 128]);
    atomicAdd(&stats[F + c], s2[tid] + s2[tid + 128]);
  }
}

// ---------------- fused BN/ReLU + segment mean/max pool + MLP head ----------------
// One 256-thread block (4 waves) per graph. Waves stride the graph's row range,
// LDS-combine partials, keep z in LDS, run the 2-layer MLP in-block.
__global__ __launch_bounds__(256) void pool_mlp_k(
    const float* __restrict__ h, const int* __restrict__ batch,
    const float* __restrict__ stats, const float* __restrict__ gamma,
    const float* __restrict__ beta, const float* __restrict__ w1,
    const float* __restrict__ b1, const float* __restrict__ w2,
    const float* __restrict__ b2, float* __restrict__ out,
    int n, float inv_n) {
  __shared__ float psum[4][128];
  __shared__ float pmax[4][128];
  __shared__ float zsh[256];
  __shared__ float part[4][64];
  const int g = blockIdx.x;
  const int tid = threadIdx.x;
  const int wave = tid >> 6, lane = tid & 63;

  // graph row range via binary search (batch is sorted); all threads redundantly
  int lo = 0, hi = n;
  while (lo < hi) { int m = (lo + hi) >> 1; if (batch[m] < g) lo = m + 1; else hi = m; }
  const int s = lo;
  hi = n;
  while (lo < hi) { int m = (lo + hi) >> 1; if (batch[m] < g + 1) lo = m + 1; else hi = m; }
  const int e = lo;

  // BN coefficients for this lane's feature pair
  const int c = lane * 2;
  float2 st = *(const float2*)(stats + c);
  float2 sq = *(const float2*)(stats + F + c);
  float2 ga = *(const float2*)(gamma + c);
  float2 be = *(const float2*)(beta + c);
  float mu0 = st.x * inv_n, mu1 = st.y * inv_n;
  float sc0 = ga.x * rsqrtf(sq.x * inv_n - mu0 * mu0 + BN_EPS);
  float sc1 = ga.y * rsqrtf(sq.y * inv_n - mu1 * mu1 + BN_EPS);
  float sh0 = be.x - mu0 * sc0;
  float sh1 = be.y - mu1 * sc1;

  float sum0 = 0.f, sum1 = 0.f, mx0 = 0.f, mx1 = 0.f;  // post-ReLU >= 0 so 0-init max is exact
#pragma unroll 2
  for (int r = s + wave; r < e; r += 4) {
    float2 v = *(const float2*)(h + (size_t)r * F + c);
    float h0 = fmaxf(fmaf(v.x, sc0, sh0), 0.f);
    float h1 = fmaxf(fmaf(v.y, sc1, sh1), 0.f);
    sum0 += h0; sum1 += h1;
    mx0 = fmaxf(mx0, h0); mx1 = fmaxf(mx1, h1);
  }
  psum[wave][c] = sum0; psum[wave][c + 1] = sum1;
  pmax[wave][c] = mx0;  pmax[wave][c + 1] = mx1;
  __syncthreads();

  if (tid < 128) {
    float sm = psum[0][tid] + psum[1][tid] + psum[2][tid] + psum[3][tid];
    float mx = fmaxf(fmaxf(pmax[0][tid], pmax[1][tid]), fmaxf(pmax[2][tid], pmax[3][tid]));
    float ic = (e > s) ? 1.0f / (float)(e - s) : 0.f;
    zsh[tid] = sm * ic;        // mean pool -> z[0:128]
    zsh[128 + tid] = mx;       // max pool  -> z[128:256]
  }
  __syncthreads();

  // hidden = relu(z @ w1 + b1): thread (wave=q, lane=j) does quarter q of the i-range
  {
    const int j = lane, q = wave;
    float acc = 0.f;
    const float* wq = w1 + (size_t)q * 64 * 64 + j;
#pragma unroll 8
    for (int i = 0; i < 64; ++i) acc = fmaf(zsh[q * 64 + i], wq[(size_t)i * 64], acc);
    part[q][j] = acc;
  }
  __syncthreads();

  if (tid < 64) {
    float hid = part[0][tid] + part[1][tid] + part[2][tid] + part[3][tid] + b1[tid];
    hid = fmaxf(hid, 0.f) * w2[tid];
    for (int off = 32; off > 0; off >>= 1) hid += __shfl_down(hid, off);
    if (tid == 0) out[g] = hid + b2[0];
  }
}

extern "C" void kernel_launch(void* const* d_in, const int* in_sizes, int n_in,
                              void* d_out, int out_size, void* d_ws, size_t ws_size,
                              hipStream_t stream) {
  const float* x      = (const float*)d_in[0];
  const int*   ei     = (const int*)d_in[1];
  const int*   batch  = (const int*)d_in[2];
  const float* Ws     = (const float*)d_in[3];
  const float* bsv    = (const float*)d_in[4];
  const float* gammas = (const float*)d_in[5];
  const float* betas  = (const float*)d_in[6];
  const float* w1     = (const float*)d_in[7];
  const float* b1     = (const float*)d_in[8];
  const float* w2     = (const float*)d_in[9];
  const float* b2     = (const float*)d_in[10];
  float* out = (float*)d_out;

  const int N = in_sizes[0] / F;          // 100000
  const int E = in_sizes[1] / 2;          // 1600000
  const int G = out_size;                 // 512
  const int L = in_sizes[3] / (F * F);    // 3
  const int* srcp = ei;
  const int* dstp = ei + E;
  const int NB = (N + 1023) / 1024;

  char* p = (char*)d_ws;
  auto carve = [&](size_t bytes) {
    char* r = p;
    p += (bytes + 255) & ~(size_t)255;
    return r;
  };
  int*   degi    = (int*)carve((size_t)NB * 1024 * 4);
  float* dinv    = (float*)carve((size_t)N * 4);
  int*   rowptr  = (int*)carve(((size_t)N + 1) * 4);
  int*   cursor  = (int*)carve((size_t)N * 4);
  int*   colsb   = (int*)carve((size_t)E * 4);
  int*   bsums   = (int*)carve(4096);
  float* bnstats = (float*)carve(2 * F * 4);
  float* bufA    = (float*)carve((size_t)N * F * 4);
  float* bufB    = (float*)carve((size_t)N * F * 4);
  (void)ws_size; (void)n_in;

  // ---- degrees + CSR build (every call: inputs identical each replay) ----
  hipMemsetAsync(degi, 0, (size_t)NB * 1024 * 4, stream);
  hist_k<<<2048, 256, 0, stream>>>(dstp, degi, E);
  scanA_k<<<NB, 256, 0, stream>>>(degi, bsums, dinv, N);
  scanB_k<<<1, 1024, 0, stream>>>(bsums, NB, rowptr, N);
  scanC_k<<<NB, 256, 0, stream>>>(degi, bsums, rowptr, cursor, N);
  scatter_k<<<2048, 256, 0, stream>>>(srcp, dstp, cursor, colsb, E);

  // ---- 3 GCN layers ----
  const float invN = 1.0f / (float)N;
  dim3 ggrid((N + 63) / 64, 2);
  for (int l = 0; l < L; ++l) {
    const float* hin = (l == 0) ? x : bufA;
    const float* st  = (l == 0) ? nullptr : bnstats;
    const float* ga  = (l == 0) ? gammas : gammas + (size_t)(l - 1) * F;
    const float* be  = (l == 0) ? betas : betas + (size_t)(l - 1) * F;
    gemm_k<<<ggrid, 256, 0, stream>>>(hin, Ws + (size_t)l * F * F, bufB, N, st, ga, be, invN);
    hipMemsetAsync(bnstats, 0, 2 * F * 4, stream);
    spmm_k<<<(N * 64 + 255) / 256, 256, 0, stream>>>(bufB, rowptr, colsb, dinv,
                                                     bsv + (size_t)l * F, bufA, N);
    stats_k<<<512, 256, 0, stream>>>(bufA, bnstats, N);
  }

  // ---- fused BN/ReLU + pooling + MLP head ----
  pool_mlp_k<<<G, 256, 0, stream>>>(bufA, batch, bnstats, gammas + (size_t)(L - 1) * F,
                                    betas + (size_t)(L - 1) * F, w1, b1, w2, b2, out, N, invN);
}

// Round 5
// 987.721 us; speedup vs baseline: 1.0095x; 1.0095x over previous
//
#include <hip/hip_runtime.h>

// GCN forward: deg/dinv -> CSR build (per call) -> 3x [GEMM(+fused BN/ReLU of prev layer,
// +dinv prescale epilogue) -> CSR SpMM aggregate (no atomics, 8-deep gather pipeline)
// -> BN stats] -> fused BN/ReLU+pool+MLP tail.

constexpr int F = 128;
constexpr float BN_EPS = 1e-5f;

// ---------------- degree histogram over dst ----------------
__global__ void hist_k(const int* __restrict__ dst, int* __restrict__ degi, int E) {
  int stride = gridDim.x * blockDim.x;
  for (int e = blockIdx.x * blockDim.x + threadIdx.x; e < E; e += stride)
    atomicAdd(&degi[dst[e]], 1);
}

// ---------------- scan stage A: per-chunk(1024) sums + dinv ----------------
__global__ __launch_bounds__(256) void scanA_k(const int* __restrict__ degi, int* __restrict__ bsums,
                                               float* __restrict__ dinv, int n) {
  __shared__ int red[256];
  int tid = threadIdx.x;
  int base = blockIdx.x * 1024 + tid * 4;
  int4 v = *(const int4*)(degi + base);  // padded region is zeroed
  if (base + 0 < n) dinv[base + 0] = rsqrtf((float)v.x + 1.0f);
  if (base + 1 < n) dinv[base + 1] = rsqrtf((float)v.y + 1.0f);
  if (base + 2 < n) dinv[base + 2] = rsqrtf((float)v.z + 1.0f);
  if (base + 3 < n) dinv[base + 3] = rsqrtf((float)v.w + 1.0f);
  red[tid] = v.x + v.y + v.z + v.w;
  __syncthreads();
  for (int off = 128; off > 0; off >>= 1) {
    if (tid < off) red[tid] += red[tid + off];
    __syncthreads();
  }
  if (tid == 0) bsums[blockIdx.x] = red[0];
}

// ---------------- scan stage B: exclusive scan of block sums (1 block) ----------------
__global__ void scanB_k(int* __restrict__ bsums, int nb, int* __restrict__ rowptr, int N) {
  __shared__ int sh[1024];
  int tid = threadIdx.x;
  for (int i = tid; i < nb; i += blockDim.x) sh[i] = bsums[i];
  __syncthreads();
  if (tid == 0) {
    int run = 0;
    for (int i = 0; i < nb; ++i) { int t = sh[i]; sh[i] = run; run += t; }
    rowptr[N] = run;  // == E
  }
  __syncthreads();
  for (int i = tid; i < nb; i += blockDim.x) bsums[i] = sh[i];
}

// ---------------- scan stage C: full exclusive scan -> rowptr & cursor ----------------
__global__ __launch_bounds__(256) void scanC_k(const int* __restrict__ degi, const int* __restrict__ bsums,
                                               int* __restrict__ rowptr, int* __restrict__ cursor, int n) {
  __shared__ int ts[256];
  int tid = threadIdx.x;
  int base = blockIdx.x * 1024 + tid * 4;
  int4 v = *(const int4*)(degi + base);
  int e0 = v.x, e1 = v.y, e2 = v.z, e3 = v.w;
  int tot = e0 + e1 + e2 + e3;
  ts[tid] = tot;
  __syncthreads();
  for (int off = 1; off < 256; off <<= 1) {
    int add = (tid >= off) ? ts[tid - off] : 0;
    __syncthreads();
    ts[tid] += add;
    __syncthreads();
  }
  int excl = ts[tid] - tot + bsums[blockIdx.x];
  int p0 = excl, p1 = p0 + e0, p2 = p1 + e1, p3 = p2 + e2;
  if (base + 0 < n) { rowptr[base + 0] = p0; cursor[base + 0] = p0; }
  if (base + 1 < n) { rowptr[base + 1] = p1; cursor[base + 1] = p1; }
  if (base + 2 < n) { rowptr[base + 2] = p2; cursor[base + 2] = p2; }
  if (base + 3 < n) { rowptr[base + 3] = p3; cursor[base + 3] = p3; }
}

// ---------------- CSR scatter: cols sorted by dst ----------------
__global__ void scatter_k(const int* __restrict__ src, const int* __restrict__ dst,
                          int* __restrict__ cursor, int* __restrict__ cols, int E) {
  int stride = gridDim.x * blockDim.x;
  for (int e = blockIdx.x * blockDim.x + threadIdx.x; e < E; e += stride) {
    int d = dst[e];
    int pos = atomicAdd(&cursor[d], 1);
    cols[pos] = src[e];
  }
}

// ---------------- fp32 GEMM: C[n,128] = dinv .* (bnrelu(A)[n,128] @ W[128,128]) --------
// Tile 64 rows x 64 cols, K=128 fully resident. A tile stored [k][row^swz] so that
// both transpose-staging stores and inner-loop float2 reads are <=2-way bank conflicts.
// Epilogue scales row r by dinv[r] so the SpMM gather needs no per-edge dinv.
__global__ __launch_bounds__(256) void gemm_k(const float* __restrict__ A, const float* __restrict__ W,
                                              float* __restrict__ C, int n,
                                              const float* __restrict__ stats,
                                              const float* __restrict__ gamma,
                                              const float* __restrict__ beta,
                                              const float* __restrict__ dinv,
                                              float inv_n) {
  __shared__ float Al[F][64];  // [k][row ^ f(k)]
  __shared__ float Wl[F][64];  // [k][col]
  const int tid = threadIdx.x;
  const int r0 = blockIdx.x * 64;
  const int c0 = blockIdx.y * 64;

  // BN scale/shift for this thread's fixed k-range (features k4..k4+3)
  const int k4 = (tid & 31) * 4;
  float sc0 = 1.f, sc1 = 1.f, sc2 = 1.f, sc3 = 1.f;
  float sh0 = 0.f, sh1 = 0.f, sh2 = 0.f, sh3 = 0.f;
  if (stats) {
    float4 s  = *(const float4*)(stats + k4);
    float4 sq = *(const float4*)(stats + F + k4);
    float4 ga = *(const float4*)(gamma + k4);
    float4 be = *(const float4*)(beta + k4);
    float mu, var, rs;
    mu = s.x * inv_n; var = sq.x * inv_n - mu * mu; rs = rsqrtf(var + BN_EPS);
    sc0 = ga.x * rs; sh0 = be.x - mu * sc0;
    mu = s.y * inv_n; var = sq.y * inv_n - mu * mu; rs = rsqrtf(var + BN_EPS);
    sc1 = ga.y * rs; sh1 = be.y - mu * sc1;
    mu = s.z * inv_n; var = sq.z * inv_n - mu * mu; rs = rsqrtf(var + BN_EPS);
    sc2 = ga.z * rs; sh2 = be.z - mu * sc2;
    mu = s.w * inv_n; var = sq.w * inv_n - mu * mu; rs = rsqrtf(var + BN_EPS);
    sc3 = ga.w * rs; sh3 = be.w - mu * sc3;
  }

  const int fsw = 2 * (tid & 31);  // == (2*(k>>2))&63 for k in [k4,k4+4)
#pragma unroll
  for (int i = 0; i < 8; ++i) {
    int idx = i * 256 + tid;
    int row = idx >> 5;          // 32 float4 per row
    int r = r0 + row;
    float4 v = {0.f, 0.f, 0.f, 0.f};
    if (r < n) v = *(const float4*)(A + (size_t)r * F + k4);
    if (stats) {
      v.x = fmaxf(v.x * sc0 + sh0, 0.f);
      v.y = fmaxf(v.y * sc1 + sh1, 0.f);
      v.z = fmaxf(v.z * sc2 + sh2, 0.f);
      v.w = fmaxf(v.w * sc3 + sh3, 0.f);
    }
    int rsw = row ^ fsw;
    Al[k4 + 0][rsw] = v.x;
    Al[k4 + 1][rsw] = v.y;
    Al[k4 + 2][rsw] = v.z;
    Al[k4 + 3][rsw] = v.w;
  }
#pragma unroll
  for (int i = 0; i < 8; ++i) {
    int idx = i * 256 + tid;
    int k = idx >> 4;            // 16 float4 per 64-col row
    int c4 = (idx & 15) * 4;
    *(float4*)&Wl[k][c4] = *(const float4*)(W + (size_t)k * F + c0 + c4);
  }
  __syncthreads();

  const int rg = tid >> 3;  // rows 2rg, 2rg+1
  const int cg = tid & 7;   // cols 8cg..8cg+7
  float acc0[8] = {0, 0, 0, 0, 0, 0, 0, 0};
  float acc1[8] = {0, 0, 0, 0, 0, 0, 0, 0};
#pragma unroll 8
  for (int k = 0; k < F; ++k) {
    int f = (2 * (k >> 2)) & 63;
    float2 a = *(const float2*)&Al[k][(2 * rg) ^ f];
    float4 w0 = *(const float4*)&Wl[k][cg * 8];
    float4 w1 = *(const float4*)&Wl[k][cg * 8 + 4];
    acc0[0] = fmaf(a.x, w0.x, acc0[0]); acc1[0] = fmaf(a.y, w0.x, acc1[0]);
    acc0[1] = fmaf(a.x, w0.y, acc0[1]); acc1[1] = fmaf(a.y, w0.y, acc1[1]);
    acc0[2] = fmaf(a.x, w0.z, acc0[2]); acc1[2] = fmaf(a.y, w0.z, acc1[2]);
    acc0[3] = fmaf(a.x, w0.w, acc0[3]); acc1[3] = fmaf(a.y, w0.w, acc1[3]);
    acc0[4] = fmaf(a.x, w1.x, acc0[4]); acc1[4] = fmaf(a.y, w1.x, acc1[4]);
    acc0[5] = fmaf(a.x, w1.y, acc0[5]); acc1[5] = fmaf(a.y, w1.y, acc1[5]);
    acc0[6] = fmaf(a.x, w1.z, acc0[6]); acc1[6] = fmaf(a.y, w1.z, acc1[6]);
    acc0[7] = fmaf(a.x, w1.w, acc0[7]); acc1[7] = fmaf(a.y, w1.w, acc1[7]);
  }
  int r = r0 + 2 * rg;
  size_t cbase = (size_t)r * F + c0 + cg * 8;
  if (r < n) {
    float d0 = dinv[r];
    float4 o0 = {acc0[0] * d0, acc0[1] * d0, acc0[2] * d0, acc0[3] * d0};
    float4 o1 = {acc0[4] * d0, acc0[5] * d0, acc0[6] * d0, acc0[7] * d0};
    *(float4*)(C + cbase) = o0;
    *(float4*)(C + cbase + 4) = o1;
  }
  if (r + 1 < n) {
    float d1 = dinv[r + 1];
    float4 o0 = {acc1[0] * d1, acc1[1] * d1, acc1[2] * d1, acc1[3] * d1};
    float4 o1 = {acc1[4] * d1, acc1[5] * d1, acc1[6] * d1, acc1[7] * d1};
    *(float4*)(C + cbase + F) = o0;
    *(float4*)(C + cbase + F + 4) = o1;
  }
}

// ---------------- CSR SpMM aggregate: one wave per dst row, no atomics ----------------
// hw is already dinv-prescaled: out[d] = dinv[d] * (sum_{s in N(d)} hw[s] + hw[d]) + bias
// 8-deep unroll: 8 wave-uniform cols scalar-loads up front, then 8 independent 512B
// row gathers in flight per wave (~4KB), tree-summed.
__global__ __launch_bounds__(256) void spmm_k(const float* __restrict__ hw, const int* __restrict__ rowptr,
                                              const int* __restrict__ cols, const float* __restrict__ dinv,
                                              const float* __restrict__ bias, float* __restrict__ out, int n) {
  int wid = (blockIdx.x * 256 + threadIdx.x) >> 6;
  int lane = threadIdx.x & 63;
  if (wid >= n) return;
  const float2* hw2 = (const float2*)hw;
  float2 v = hw2[(size_t)wid * 64 + lane];
  float ax = v.x, ay = v.y;  // self-loop term (hw already dinv-scaled)
  int j = rowptr[wid];
  const int e = rowptr[wid + 1];
  for (; j + 8 <= e; j += 8) {
    int c0 = cols[j + 0], c1 = cols[j + 1], c2 = cols[j + 2], c3 = cols[j + 3];
    int c4 = cols[j + 4], c5 = cols[j + 5], c6 = cols[j + 6], c7 = cols[j + 7];
    float2 v0 = hw2[(size_t)c0 * 64 + lane];
    float2 v1 = hw2[(size_t)c1 * 64 + lane];
    float2 v2 = hw2[(size_t)c2 * 64 + lane];
    float2 v3 = hw2[(size_t)c3 * 64 + lane];
    float2 v4 = hw2[(size_t)c4 * 64 + lane];
    float2 v5 = hw2[(size_t)c5 * 64 + lane];
    float2 v6 = hw2[(size_t)c6 * 64 + lane];
    float2 v7 = hw2[(size_t)c7 * 64 + lane];
    float sx0 = v0.x + v1.x, sx1 = v2.x + v3.x, sx2 = v4.x + v5.x, sx3 = v6.x + v7.x;
    float sy0 = v0.y + v1.y, sy1 = v2.y + v3.y, sy2 = v4.y + v5.y, sy3 = v6.y + v7.y;
    ax += (sx0 + sx1) + (sx2 + sx3);
    ay += (sy0 + sy1) + (sy2 + sy3);
  }
  if (j + 4 <= e) {
    int c0 = cols[j + 0], c1 = cols[j + 1], c2 = cols[j + 2], c3 = cols[j + 3];
    float2 v0 = hw2[(size_t)c0 * 64 + lane];
    float2 v1 = hw2[(size_t)c1 * 64 + lane];
    float2 v2 = hw2[(size_t)c2 * 64 + lane];
    float2 v3 = hw2[(size_t)c3 * 64 + lane];
    ax += (v0.x + v1.x) + (v2.x + v3.x);
    ay += (v0.y + v1.y) + (v2.y + v3.y);
    j += 4;
  }
  for (; j < e; ++j) {
    int c = cols[j];
    float2 vv = hw2[(size_t)c * 64 + lane];
    ax += vv.x;
    ay += vv.y;
  }
  float di = dinv[wid];
  float2 b = ((const float2*)bias)[lane];
  float2 o;
  o.x = fmaf(di, ax, b.x);
  o.y = fmaf(di, ay, b.y);
  ((float2*)out)[(size_t)wid * 64 + lane] = o;
}

// ---------------- BN statistics: sum & sumsq per feature ----------------
__global__ __launch_bounds__(256) void stats_k(const float* __restrict__ h, float* __restrict__ stats, int n) {
  __shared__ float s1[256], s2[256];
  int tid = threadIdx.x;
  int c = tid & 127, half = tid >> 7;
  float a = 0.f, b = 0.f;
  for (int r = blockIdx.x * 2 + half; r < n; r += gridDim.x * 2) {
    float v = h[(size_t)r * F + c];
    a += v;
    b += v * v;
  }
  s1[tid] = a; s2[tid] = b;
  __syncthreads();
  if (tid < 128) {
    atomicAdd(&stats[c], s1[tid] + s1[tid + 128]);
    atomicAdd(&stats[F + c], s2[tid] + s2[tid + 128]);
  }
}

// ---------------- fused BN/ReLU + segment mean/max pool + MLP head ----------------
// One 256-thread block (4 waves) per graph. Waves stride the graph's row range,
// LDS-combine partials, keep z in LDS, run the 2-layer MLP in-block.
__global__ __launch_bounds__(256) void pool_mlp_k(
    const float* __restrict__ h, const int* __restrict__ batch,
    const float* __restrict__ stats, const float* __restrict__ gamma,
    const float* __restrict__ beta, const float* __restrict__ w1,
    const float* __restrict__ b1, const float* __restrict__ w2,
    const float* __restrict__ b2, float* __restrict__ out,
    int n, float inv_n) {
  __shared__ float psum[4][128];
  __shared__ float pmax[4][128];
  __shared__ float zsh[256];
  __shared__ float part[4][64];
  const int g = blockIdx.x;
  const int tid = threadIdx.x;
  const int wave = tid >> 6, lane = tid & 63;

  // graph row range via binary search (batch is sorted); all threads redundantly
  int lo = 0, hi = n;
  while (lo < hi) { int m = (lo + hi) >> 1; if (batch[m] < g) lo = m + 1; else hi = m; }
  const int s = lo;
  hi = n;
  while (lo < hi) { int m = (lo + hi) >> 1; if (batch[m] < g + 1) lo = m + 1; else hi = m; }
  const int e = lo;

  // BN coefficients for this lane's feature pair
  const int c = lane * 2;
  float2 st = *(const float2*)(stats + c);
  float2 sq = *(const float2*)(stats + F + c);
  float2 ga = *(const float2*)(gamma + c);
  float2 be = *(const float2*)(beta + c);
  float mu0 = st.x * inv_n, mu1 = st.y * inv_n;
  float sc0 = ga.x * rsqrtf(sq.x * inv_n - mu0 * mu0 + BN_EPS);
  float sc1 = ga.y * rsqrtf(sq.y * inv_n - mu1 * mu1 + BN_EPS);
  float sh0 = be.x - mu0 * sc0;
  float sh1 = be.y - mu1 * sc1;

  float sum0 = 0.f, sum1 = 0.f, mx0 = 0.f, mx1 = 0.f;  // post-ReLU >= 0 so 0-init max is exact
#pragma unroll 2
  for (int r = s + wave; r < e; r += 4) {
    float2 v = *(const float2*)(h + (size_t)r * F + c);
    float h0 = fmaxf(fmaf(v.x, sc0, sh0), 0.f);
    float h1 = fmaxf(fmaf(v.y, sc1, sh1), 0.f);
    sum0 += h0; sum1 += h1;
    mx0 = fmaxf(mx0, h0); mx1 = fmaxf(mx1, h1);
  }
  psum[wave][c] = sum0; psum[wave][c + 1] = sum1;
  pmax[wave][c] = mx0;  pmax[wave][c + 1] = mx1;
  __syncthreads();

  if (tid < 128) {
    float sm = psum[0][tid] + psum[1][tid] + psum[2][tid] + psum[3][tid];
    float mx = fmaxf(fmaxf(pmax[0][tid], pmax[1][tid]), fmaxf(pmax[2][tid], pmax[3][tid]));
    float ic = (e > s) ? 1.0f / (float)(e - s) : 0.f;
    zsh[tid] = sm * ic;        // mean pool -> z[0:128]
    zsh[128 + tid] = mx;       // max pool  -> z[128:256]
  }
  __syncthreads();

  // hidden = relu(z @ w1 + b1): thread (wave=q, lane=j) does quarter q of the i-range
  {
    const int j = lane, q = wave;
    float acc = 0.f;
    const float* wq = w1 + (size_t)q * 64 * 64 + j;
#pragma unroll 8
    for (int i = 0; i < 64; ++i) acc = fmaf(zsh[q * 64 + i], wq[(size_t)i * 64], acc);
    part[q][j] = acc;
  }
  __syncthreads();

  if (tid < 64) {
    float hid = part[0][tid] + part[1][tid] + part[2][tid] + part[3][tid] + b1[tid];
    hid = fmaxf(hid, 0.f) * w2[tid];
    for (int off = 32; off > 0; off >>= 1) hid += __shfl_down(hid, off);
    if (tid == 0) out[g] = hid + b2[0];
  }
}

extern "C" void kernel_launch(void* const* d_in, const int* in_sizes, int n_in,
                              void* d_out, int out_size, void* d_ws, size_t ws_size,
                              hipStream_t stream) {
  const float* x      = (const float*)d_in[0];
  const int*   ei     = (const int*)d_in[1];
  const int*   batch  = (const int*)d_in[2];
  const float* Ws     = (const float*)d_in[3];
  const float* bsv    = (const float*)d_in[4];
  const float* gammas = (const float*)d_in[5];
  const float* betas  = (const float*)d_in[6];
  const float* w1     = (const float*)d_in[7];
  const float* b1     = (const float*)d_in[8];
  const float* w2     = (const float*)d_in[9];
  const float* b2     = (const float*)d_in[10];
  float* out = (float*)d_out;

  const int N = in_sizes[0] / F;          // 100000
  const int E = in_sizes[1] / 2;          // 1600000
  const int G = out_size;                 // 512
  const int L = in_sizes[3] / (F * F);    // 3
  const int* srcp = ei;
  const int* dstp = ei + E;
  const int NB = (N + 1023) / 1024;

  char* p = (char*)d_ws;
  auto carve = [&](size_t bytes) {
    char* r = p;
    p += (bytes + 255) & ~(size_t)255;
    return r;
  };
  int*   degi    = (int*)carve((size_t)NB * 1024 * 4);
  float* dinv    = (float*)carve((size_t)N * 4);
  int*   rowptr  = (int*)carve(((size_t)N + 1) * 4);
  int*   cursor  = (int*)carve((size_t)N * 4);
  int*   colsb   = (int*)carve((size_t)E * 4);
  int*   bsums   = (int*)carve(4096);
  float* bnstats = (float*)carve(2 * F * 4);
  float* bufA    = (float*)carve((size_t)N * F * 4);
  float* bufB    = (float*)carve((size_t)N * F * 4);
  (void)ws_size; (void)n_in;

  // ---- degrees + CSR build (every call: inputs identical each replay) ----
  hipMemsetAsync(degi, 0, (size_t)NB * 1024 * 4, stream);
  hist_k<<<2048, 256, 0, stream>>>(dstp, degi, E);
  scanA_k<<<NB, 256, 0, stream>>>(degi, bsums, dinv, N);
  scanB_k<<<1, 1024, 0, stream>>>(bsums, NB, rowptr, N);
  scanC_k<<<NB, 256, 0, stream>>>(degi, bsums, rowptr, cursor, N);
  scatter_k<<<2048, 256, 0, stream>>>(srcp, dstp, cursor, colsb, E);

  // ---- 3 GCN layers ----
  const float invN = 1.0f / (float)N;
  dim3 ggrid((N + 63) / 64, 2);
  for (int l = 0; l < L; ++l) {
    const float* hin = (l == 0) ? x : bufA;
    const float* st  = (l == 0) ? nullptr : bnstats;
    const float* ga  = (l == 0) ? gammas : gammas + (size_t)(l - 1) * F;
    const float* be  = (l == 0) ? betas : betas + (size_t)(l - 1) * F;
    gemm_k<<<ggrid, 256, 0, stream>>>(hin, Ws + (size_t)l * F * F, bufB, N, st, ga, be, dinv, invN);
    hipMemsetAsync(bnstats, 0, 2 * F * 4, stream);
    spmm_k<<<(N * 64 + 255) / 256, 256, 0, stream>>>(bufB, rowptr, colsb, dinv,
                                                     bsv + (size_t)l * F, bufA, N);
    stats_k<<<512, 256, 0, stream>>>(bufA, bnstats, N);
  }

  // ---- fused BN/ReLU + pooling + MLP head ----
  pool_mlp_k<<<G, 256, 0, stream>>>(bufA, batch, bnstats, gammas + (size_t)(L - 1) * F,
                                    betas + (size_t)(L - 1) * F, w1, b1, w2, b2, out, N, invN);
}

// Round 6
// 766.273 us; speedup vs baseline: 1.3012x; 1.2890x over previous
//
#include <hip/hip_runtime.h>
#include <hip/hip_fp16.h>

// GCN forward: deg/dinv -> CSR build (bucketed 2-pass partition, low write-amp) ->
// 3x [GEMM(+fused BN/ReLU, +dinv prescale, fp16 output table) -> CSR SpMM gather (fp16
// table, fp32 accum, no atomics) -> BN stats] -> fused BN/ReLU+pool+MLP tail.

constexpr int F = 128;
constexpr float BN_EPS = 1e-5f;
constexpr int NB1 = 256;   // partition blocks
constexpr int NBKT = 256;  // buckets of 512 node ids (dst >> 9)

// ---------------- degree histogram over dst ----------------
__global__ void hist_k(const int* __restrict__ dst, int* __restrict__ degi, int E) {
  int stride = gridDim.x * blockDim.x;
  for (int e = blockIdx.x * blockDim.x + threadIdx.x; e < E; e += stride)
    atomicAdd(&degi[dst[e]], 1);
}

// ---------------- scan stage A: per-chunk(1024) sums + dinv ----------------
__global__ __launch_bounds__(256) void scanA_k(const int* __restrict__ degi, int* __restrict__ bsums,
                                               float* __restrict__ dinv, int n) {
  __shared__ int red[256];
  int tid = threadIdx.x;
  int base = blockIdx.x * 1024 + tid * 4;
  int4 v = *(const int4*)(degi + base);  // padded region is zeroed
  if (base + 0 < n) dinv[base + 0] = rsqrtf((float)v.x + 1.0f);
  if (base + 1 < n) dinv[base + 1] = rsqrtf((float)v.y + 1.0f);
  if (base + 2 < n) dinv[base + 2] = rsqrtf((float)v.z + 1.0f);
  if (base + 3 < n) dinv[base + 3] = rsqrtf((float)v.w + 1.0f);
  red[tid] = v.x + v.y + v.z + v.w;
  __syncthreads();
  for (int off = 128; off > 0; off >>= 1) {
    if (tid < off) red[tid] += red[tid + off];
    __syncthreads();
  }
  if (tid == 0) bsums[blockIdx.x] = red[0];
}

// ---------------- scan stage B: exclusive scan of block sums (1 block) ----------------
__global__ void scanB_k(int* __restrict__ bsums, int nb, int* __restrict__ rowptr, int N) {
  __shared__ int sh[1024];
  int tid = threadIdx.x;
  for (int i = tid; i < nb; i += blockDim.x) sh[i] = bsums[i];
  __syncthreads();
  if (tid == 0) {
    int run = 0;
    for (int i = 0; i < nb; ++i) { int t = sh[i]; sh[i] = run; run += t; }
    rowptr[N] = run;  // == E
  }
  __syncthreads();
  for (int i = tid; i < nb; i += blockDim.x) bsums[i] = sh[i];
}

// ---------------- scan stage C: full exclusive scan -> rowptr ----------------
__global__ __launch_bounds__(256) void scanC_k(const int* __restrict__ degi, const int* __restrict__ bsums,
                                               int* __restrict__ rowptr, int n) {
  __shared__ int ts[256];
  int tid = threadIdx.x;
  int base = blockIdx.x * 1024 + tid * 4;
  int4 v = *(const int4*)(degi + base);
  int e0 = v.x, e1 = v.y, e2 = v.z, e3 = v.w;
  int tot = e0 + e1 + e2 + e3;
  ts[tid] = tot;
  __syncthreads();
  for (int off = 1; off < 256; off <<= 1) {
    int add = (tid >= off) ? ts[tid - off] : 0;
    __syncthreads();
    ts[tid] += add;
    __syncthreads();
  }
  int excl = ts[tid] - tot + bsums[blockIdx.x];
  int p0 = excl, p1 = p0 + e0, p2 = p1 + e1, p3 = p2 + e2;
  if (base + 0 < n) rowptr[base + 0] = p0;
  if (base + 1 < n) rowptr[base + 1] = p1;
  if (base + 2 < n) rowptr[base + 2] = p2;
  if (base + 3 < n) rowptr[base + 3] = p3;
}

// ---------------- CSR build K1: per-(block,bucket) histogram ----------------
__global__ __launch_bounds__(256) void part1_k(const int* __restrict__ dst, int* __restrict__ hist, int E) {
  __shared__ int cnt[NBKT];
  int tid = threadIdx.x;
  cnt[tid] = 0;
  __syncthreads();
  int chunk = (E + NB1 - 1) / NB1;
  int s = blockIdx.x * chunk, e = min(s + chunk, E);
  for (int i = s + tid; i < e; i += 256) atomicAdd(&cnt[dst[i] >> 9], 1);
  __syncthreads();
  hist[blockIdx.x * NBKT + tid] = cnt[tid];  // [blk][bkt], coalesced
}

// ---------------- CSR build K2: exclusive scan in (bucket-major, block-minor) order ----
__global__ __launch_bounds__(1024) void part_scan_k(const int* __restrict__ hist, int* __restrict__ base) {
  __shared__ int sh[1024];
  const int t = threadIdx.x;
  const int per = (NBKT * NB1) / 1024;  // 64
  int sum = 0;
  for (int j = 0; j < per; ++j) {
    int i = t * per + j;               // i = b*NB1 + blk
    sum += hist[(i & (NB1 - 1)) * NBKT + (i >> 8)];
  }
  sh[t] = sum;
  __syncthreads();
  for (int off = 1; off < 1024; off <<= 1) {
    int v = (t >= off) ? sh[t - off] : 0;
    __syncthreads();
    sh[t] += v;
    __syncthreads();
  }
  int run = sh[t] - sum;  // exclusive prefix
  for (int j = 0; j < per; ++j) {
    int i = t * per + j;
    int v = hist[(i & (NB1 - 1)) * NBKT + (i >> 8)];
    base[i] = run;  // base laid out i = b*NB1 + blk
    run += v;
  }
}

// ---------------- CSR build K3: partition (src,dst) pairs into buckets ----------------
__global__ __launch_bounds__(256) void part2_k(const int* __restrict__ src, const int* __restrict__ dst,
                                               const int* __restrict__ base, int2* __restrict__ pairbuf, int E) {
  __shared__ int cnt[NBKT];
  __shared__ int baseL[NBKT];
  int tid = threadIdx.x;
  cnt[tid] = 0;
  baseL[tid] = base[tid * NB1 + blockIdx.x];  // base[b][blk] for this blk
  __syncthreads();
  int chunk = (E + NB1 - 1) / NB1;
  int s = blockIdx.x * chunk, e = min(s + chunk, E);
  for (int i = s + tid; i < e; i += 256) {
    int sv = src[i], dv = dst[i];
    int b = dv >> 9;
    int r = atomicAdd(&cnt[b], 1);
    pairbuf[baseL[b] + r] = make_int2(sv, dv);
  }
}

// ---------------- CSR build K4: per-bucket final scatter with LDS cursors ------------
// Bucket b owns nodes [b*512,(b+1)*512); its cols region (~32KB) stays L2-hot.
__global__ __launch_bounds__(256) void scat2_k(const int2* __restrict__ pairbuf, const int* __restrict__ base,
                                               const int* __restrict__ rowptr, int* __restrict__ cols,
                                               int N, int E) {
  __shared__ int curL[512];
  const int b = blockIdx.x;
  const int tid = threadIdx.x;
  const int n0 = b << 9;
  for (int i = tid; i < 512; i += 256) {
    int node = n0 + i;
    curL[i] = (node < N) ? rowptr[node] : 0;
  }
  __syncthreads();
  int lo = base[b * NB1];
  int hi = (b == NBKT - 1) ? E : base[(b + 1) * NB1];
  for (int t = lo + tid; t < hi; t += 256) {
    int2 pr = pairbuf[t];
    int pos = atomicAdd(&curL[pr.y - n0], 1);
    cols[pos] = pr.x;
  }
}

// ---------------- fp32 GEMM: Ch[n,128] = fp16( dinv .* (bnrelu(A) @ W) ) --------------
// Tile 64x64, K=128 resident. A tile [k][row^swz] keeps staging stores and inner
// float2 reads <=2-way bank conflicts. Epilogue: dinv prescale + fp16 pack.
__global__ __launch_bounds__(256) void gemm_k(const float* __restrict__ A, const float* __restrict__ W,
                                              __half* __restrict__ Ch, int n,
                                              const float* __restrict__ stats,
                                              const float* __restrict__ gamma,
                                              const float* __restrict__ beta,
                                              const float* __restrict__ dinv,
                                              float inv_n) {
  __shared__ float Al[F][64];  // [k][row ^ f(k)]
  __shared__ float Wl[F][64];  // [k][col]
  const int tid = threadIdx.x;
  const int r0 = blockIdx.x * 64;
  const int c0 = blockIdx.y * 64;

  const int k4 = (tid & 31) * 4;
  float sc0 = 1.f, sc1 = 1.f, sc2 = 1.f, sc3 = 1.f;
  float sh0 = 0.f, sh1 = 0.f, sh2 = 0.f, sh3 = 0.f;
  if (stats) {
    float4 s  = *(const float4*)(stats + k4);
    float4 sq = *(const float4*)(stats + F + k4);
    float4 ga = *(const float4*)(gamma + k4);
    float4 be = *(const float4*)(beta + k4);
    float mu, var, rs;
    mu = s.x * inv_n; var = sq.x * inv_n - mu * mu; rs = rsqrtf(var + BN_EPS);
    sc0 = ga.x * rs; sh0 = be.x - mu * sc0;
    mu = s.y * inv_n; var = sq.y * inv_n - mu * mu; rs = rsqrtf(var + BN_EPS);
    sc1 = ga.y * rs; sh1 = be.y - mu * sc1;
    mu = s.z * inv_n; var = sq.z * inv_n - mu * mu; rs = rsqrtf(var + BN_EPS);
    sc2 = ga.z * rs; sh2 = be.z - mu * sc2;
    mu = s.w * inv_n; var = sq.w * inv_n - mu * mu; rs = rsqrtf(var + BN_EPS);
    sc3 = ga.w * rs; sh3 = be.w - mu * sc3;
  }

  const int fsw = 2 * (tid & 31);
#pragma unroll
  for (int i = 0; i < 8; ++i) {
    int idx = i * 256 + tid;
    int row = idx >> 5;
    int r = r0 + row;
    float4 v = {0.f, 0.f, 0.f, 0.f};
    if (r < n) v = *(const float4*)(A + (size_t)r * F + k4);
    if (stats) {
      v.x = fmaxf(v.x * sc0 + sh0, 0.f);
      v.y = fmaxf(v.y * sc1 + sh1, 0.f);
      v.z = fmaxf(v.z * sc2 + sh2, 0.f);
      v.w = fmaxf(v.w * sc3 + sh3, 0.f);
    }
    int rsw = row ^ fsw;
    Al[k4 + 0][rsw] = v.x;
    Al[k4 + 1][rsw] = v.y;
    Al[k4 + 2][rsw] = v.z;
    Al[k4 + 3][rsw] = v.w;
  }
#pragma unroll
  for (int i = 0; i < 8; ++i) {
    int idx = i * 256 + tid;
    int k = idx >> 4;
    int c4 = (idx & 15) * 4;
    *(float4*)&Wl[k][c4] = *(const float4*)(W + (size_t)k * F + c0 + c4);
  }
  __syncthreads();

  const int rg = tid >> 3;
  const int cg = tid & 7;
  float acc0[8] = {0, 0, 0, 0, 0, 0, 0, 0};
  float acc1[8] = {0, 0, 0, 0, 0, 0, 0, 0};
#pragma unroll 8
  for (int k = 0; k < F; ++k) {
    int f = (2 * (k >> 2)) & 63;
    float2 a = *(const float2*)&Al[k][(2 * rg) ^ f];
    float4 w0 = *(const float4*)&Wl[k][cg * 8];
    float4 w1 = *(const float4*)&Wl[k][cg * 8 + 4];
    acc0[0] = fmaf(a.x, w0.x, acc0[0]); acc1[0] = fmaf(a.y, w0.x, acc1[0]);
    acc0[1] = fmaf(a.x, w0.y, acc0[1]); acc1[1] = fmaf(a.y, w0.y, acc1[1]);
    acc0[2] = fmaf(a.x, w0.z, acc0[2]); acc1[2] = fmaf(a.y, w0.z, acc1[2]);
    acc0[3] = fmaf(a.x, w0.w, acc0[3]); acc1[3] = fmaf(a.y, w0.w, acc1[3]);
    acc0[4] = fmaf(a.x, w1.x, acc0[4]); acc1[4] = fmaf(a.y, w1.x, acc1[4]);
    acc0[5] = fmaf(a.x, w1.y, acc0[5]); acc1[5] = fmaf(a.y, w1.y, acc1[5]);
    acc0[6] = fmaf(a.x, w1.z, acc0[6]); acc1[6] = fmaf(a.y, w1.z, acc1[6]);
    acc0[7] = fmaf(a.x, w1.w, acc0[7]); acc1[7] = fmaf(a.y, w1.w, acc1[7]);
  }
  int r = r0 + 2 * rg;
  size_t cbase = (size_t)r * F + c0 + cg * 8;
  if (r < n) {
    float d0 = dinv[r];
    union { __half2 h[4]; int4 i4; } u;
    u.h[0] = __floats2half2_rn(acc0[0] * d0, acc0[1] * d0);
    u.h[1] = __floats2half2_rn(acc0[2] * d0, acc0[3] * d0);
    u.h[2] = __floats2half2_rn(acc0[4] * d0, acc0[5] * d0);
    u.h[3] = __floats2half2_rn(acc0[6] * d0, acc0[7] * d0);
    *(int4*)(Ch + cbase) = u.i4;
  }
  if (r + 1 < n) {
    float d1 = dinv[r + 1];
    union { __half2 h[4]; int4 i4; } u;
    u.h[0] = __floats2half2_rn(acc1[0] * d1, acc1[1] * d1);
    u.h[1] = __floats2half2_rn(acc1[2] * d1, acc1[3] * d1);
    u.h[2] = __floats2half2_rn(acc1[4] * d1, acc1[5] * d1);
    u.h[3] = __floats2half2_rn(acc1[6] * d1, acc1[7] * d1);
    *(int4*)(Ch + cbase + F) = u.i4;
  }
}

// ---------------- CSR SpMM aggregate: one wave per dst row, fp16 gather --------------
// hw is dinv-prescaled fp16: out[d] = dinv[d]*(sum_{s in N(d)} hw[s] + hw[d]) + bias
__global__ __launch_bounds__(256) void spmm_k(const __half* __restrict__ hw, const int* __restrict__ rowptr,
                                              const int* __restrict__ cols, const float* __restrict__ dinv,
                                              const float* __restrict__ bias, float* __restrict__ out, int n) {
  int wid = (blockIdx.x * 256 + threadIdx.x) >> 6;
  int lane = threadIdx.x & 63;
  if (wid >= n) return;
  const __half2* hw2 = (const __half2*)hw;
  float2 vf = __half22float2(hw2[(size_t)wid * 64 + lane]);
  float ax = vf.x, ay = vf.y;  // self-loop term
  int j = rowptr[wid];
  const int e = rowptr[wid + 1];
  for (; j + 8 <= e; j += 8) {
    int c0 = cols[j + 0], c1 = cols[j + 1], c2 = cols[j + 2], c3 = cols[j + 3];
    int c4 = cols[j + 4], c5 = cols[j + 5], c6 = cols[j + 6], c7 = cols[j + 7];
    float2 v0 = __half22float2(hw2[(size_t)c0 * 64 + lane]);
    float2 v1 = __half22float2(hw2[(size_t)c1 * 64 + lane]);
    float2 v2 = __half22float2(hw2[(size_t)c2 * 64 + lane]);
    float2 v3 = __half22float2(hw2[(size_t)c3 * 64 + lane]);
    float2 v4 = __half22float2(hw2[(size_t)c4 * 64 + lane]);
    float2 v5 = __half22float2(hw2[(size_t)c5 * 64 + lane]);
    float2 v6 = __half22float2(hw2[(size_t)c6 * 64 + lane]);
    float2 v7 = __half22float2(hw2[(size_t)c7 * 64 + lane]);
    ax += ((v0.x + v1.x) + (v2.x + v3.x)) + ((v4.x + v5.x) + (v6.x + v7.x));
    ay += ((v0.y + v1.y) + (v2.y + v3.y)) + ((v4.y + v5.y) + (v6.y + v7.y));
  }
  if (j + 4 <= e) {
    int c0 = cols[j + 0], c1 = cols[j + 1], c2 = cols[j + 2], c3 = cols[j + 3];
    float2 v0 = __half22float2(hw2[(size_t)c0 * 64 + lane]);
    float2 v1 = __half22float2(hw2[(size_t)c1 * 64 + lane]);
    float2 v2 = __half22float2(hw2[(size_t)c2 * 64 + lane]);
    float2 v3 = __half22float2(hw2[(size_t)c3 * 64 + lane]);
    ax += (v0.x + v1.x) + (v2.x + v3.x);
    ay += (v0.y + v1.y) + (v2.y + v3.y);
    j += 4;
  }
  for (; j < e; ++j) {
    float2 vv = __half22float2(hw2[(size_t)cols[j] * 64 + lane]);
    ax += vv.x;
    ay += vv.y;
  }
  float di = dinv[wid];
  float2 b = ((const float2*)bias)[lane];
  float2 o;
  o.x = fmaf(di, ax, b.x);
  o.y = fmaf(di, ay, b.y);
  ((float2*)out)[(size_t)wid * 64 + lane] = o;
}

// ---------------- BN statistics: sum & sumsq per feature ----------------
__global__ __launch_bounds__(256) void stats_k(const float* __restrict__ h, float* __restrict__ stats, int n) {
  __shared__ float s1[256], s2[256];
  int tid = threadIdx.x;
  int c = tid & 127, half = tid >> 7;
  float a = 0.f, b = 0.f;
  for (int r = blockIdx.x * 2 + half; r < n; r += gridDim.x * 2) {
    float v = h[(size_t)r * F + c];
    a += v;
    b += v * v;
  }
  s1[tid] = a; s2[tid] = b;
  __syncthreads();
  if (tid < 128) {
    atomicAdd(&stats[c], s1[tid] + s1[tid + 128]);
    atomicAdd(&stats[F + c], s2[tid] + s2[tid + 128]);
  }
}

// ---------------- fused BN/ReLU + segment mean/max pool + MLP head ----------------
__global__ __launch_bounds__(256) void pool_mlp_k(
    const float* __restrict__ h, const int* __restrict__ batch,
    const float* __restrict__ stats, const float* __restrict__ gamma,
    const float* __restrict__ beta, const float* __restrict__ w1,
    const float* __restrict__ b1, const float* __restrict__ w2,
    const float* __restrict__ b2, float* __restrict__ out,
    int n, float inv_n) {
  __shared__ float psum[4][128];
  __shared__ float pmax[4][128];
  __shared__ float zsh[256];
  __shared__ float part[4][64];
  const int g = blockIdx.x;
  const int tid = threadIdx.x;
  const int wave = tid >> 6, lane = tid & 63;

  int lo = 0, hi = n;
  while (lo < hi) { int m = (lo + hi) >> 1; if (batch[m] < g) lo = m + 1; else hi = m; }
  const int s = lo;
  hi = n;
  while (lo < hi) { int m = (lo + hi) >> 1; if (batch[m] < g + 1) lo = m + 1; else hi = m; }
  const int e = lo;

  const int c = lane * 2;
  float2 st = *(const float2*)(stats + c);
  float2 sq = *(const float2*)(stats + F + c);
  float2 ga = *(const float2*)(gamma + c);
  float2 be = *(const float2*)(beta + c);
  float mu0 = st.x * inv_n, mu1 = st.y * inv_n;
  float sc0 = ga.x * rsqrtf(sq.x * inv_n - mu0 * mu0 + BN_EPS);
  float sc1 = ga.y * rsqrtf(sq.y * inv_n - mu1 * mu1 + BN_EPS);
  float sh0 = be.x - mu0 * sc0;
  float sh1 = be.y - mu1 * sc1;

  float sum0 = 0.f, sum1 = 0.f, mx0 = 0.f, mx1 = 0.f;  // post-ReLU >= 0
#pragma unroll 2
  for (int r = s + wave; r < e; r += 4) {
    float2 v = *(const float2*)(h + (size_t)r * F + c);
    float h0 = fmaxf(fmaf(v.x, sc0, sh0), 0.f);
    float h1 = fmaxf(fmaf(v.y, sc1, sh1), 0.f);
    sum0 += h0; sum1 += h1;
    mx0 = fmaxf(mx0, h0); mx1 = fmaxf(mx1, h1);
  }
  psum[wave][c] = sum0; psum[wave][c + 1] = sum1;
  pmax[wave][c] = mx0;  pmax[wave][c + 1] = mx1;
  __syncthreads();

  if (tid < 128) {
    float sm = psum[0][tid] + psum[1][tid] + psum[2][tid] + psum[3][tid];
    float mx = fmaxf(fmaxf(pmax[0][tid], pmax[1][tid]), fmaxf(pmax[2][tid], pmax[3][tid]));
    float ic = (e > s) ? 1.0f / (float)(e - s) : 0.f;
    zsh[tid] = sm * ic;
    zsh[128 + tid] = mx;
  }
  __syncthreads();

  {
    const int j = lane, q = wave;
    float acc = 0.f;
    const float* wq = w1 + (size_t)q * 64 * 64 + j;
#pragma unroll 8
    for (int i = 0; i < 64; ++i) acc = fmaf(zsh[q * 64 + i], wq[(size_t)i * 64], acc);
    part[q][j] = acc;
  }
  __syncthreads();

  if (tid < 64) {
    float hid = part[0][tid] + part[1][tid] + part[2][tid] + part[3][tid] + b1[tid];
    hid = fmaxf(hid, 0.f) * w2[tid];
    for (int off = 32; off > 0; off >>= 1) hid += __shfl_down(hid, off);
    if (tid == 0) out[g] = hid + b2[0];
  }
}

extern "C" void kernel_launch(void* const* d_in, const int* in_sizes, int n_in,
                              void* d_out, int out_size, void* d_ws, size_t ws_size,
                              hipStream_t stream) {
  const float* x      = (const float*)d_in[0];
  const int*   ei     = (const int*)d_in[1];
  const int*   batch  = (const int*)d_in[2];
  const float* Ws     = (const float*)d_in[3];
  const float* bsv    = (const float*)d_in[4];
  const float* gammas = (const float*)d_in[5];
  const float* betas  = (const float*)d_in[6];
  const float* w1     = (const float*)d_in[7];
  const float* b1     = (const float*)d_in[8];
  const float* w2     = (const float*)d_in[9];
  const float* b2     = (const float*)d_in[10];
  float* out = (float*)d_out;

  const int N = in_sizes[0] / F;          // 100000
  const int E = in_sizes[1] / 2;          // 1600000
  const int G = out_size;                 // 512
  const int L = in_sizes[3] / (F * F);    // 3
  const int* srcp = ei;
  const int* dstp = ei + E;
  const int NB = (N + 1023) / 1024;

  char* p = (char*)d_ws;
  auto carve = [&](size_t bytes) {
    char* r = p;
    p += (bytes + 255) & ~(size_t)255;
    return r;
  };
  int*    degi    = (int*)carve((size_t)NB * 1024 * 4);
  float*  dinv    = (float*)carve((size_t)N * 4);
  int*    rowptr  = (int*)carve(((size_t)N + 1) * 4);
  int*    colsb   = (int*)carve((size_t)E * 4);
  int*    bsums   = (int*)carve(4096);
  int*    hist    = (int*)carve((size_t)NB1 * NBKT * 4);
  int*    pbase   = (int*)carve((size_t)NB1 * NBKT * 4);
  int2*   pairbuf = (int2*)carve((size_t)E * 8);
  float*  bnstats = (float*)carve(2 * F * 4);
  __half* hwh     = (__half*)carve((size_t)N * F * 2);
  float*  bufA    = (float*)carve((size_t)N * F * 4);
  (void)ws_size; (void)n_in;

  // ---- degrees + bucketed CSR build (every call) ----
  hipMemsetAsync(degi, 0, (size_t)NB * 1024 * 4, stream);
  hist_k<<<2048, 256, 0, stream>>>(dstp, degi, E);
  scanA_k<<<NB, 256, 0, stream>>>(degi, bsums, dinv, N);
  scanB_k<<<1, 1024, 0, stream>>>(bsums, NB, rowptr, N);
  scanC_k<<<NB, 256, 0, stream>>>(degi, bsums, rowptr, N);
  part1_k<<<NB1, 256, 0, stream>>>(dstp, hist, E);
  part_scan_k<<<1, 1024, 0, stream>>>(hist, pbase);
  part2_k<<<NB1, 256, 0, stream>>>(srcp, dstp, pbase, pairbuf, E);
  scat2_k<<<NBKT, 256, 0, stream>>>(pairbuf, pbase, rowptr, colsb, N, E);

  // ---- 3 GCN layers ----
  const float invN = 1.0f / (float)N;
  dim3 ggrid((N + 63) / 64, 2);
  for (int l = 0; l < L; ++l) {
    const float* hin = (l == 0) ? x : bufA;
    const float* st  = (l == 0) ? nullptr : bnstats;
    const float* ga  = (l == 0) ? gammas : gammas + (size_t)(l - 1) * F;
    const float* be  = (l == 0) ? betas : betas + (size_t)(l - 1) * F;
    gemm_k<<<ggrid, 256, 0, stream>>>(hin, Ws + (size_t)l * F * F, hwh, N, st, ga, be, dinv, invN);
    hipMemsetAsync(bnstats, 0, 2 * F * 4, stream);
    spmm_k<<<(N * 64 + 255) / 256, 256, 0, stream>>>(hwh, rowptr, colsb, dinv,
                                                     bsv + (size_t)l * F, bufA, N);
    stats_k<<<512, 256, 0, stream>>>(bufA, bnstats, N);
  }

  // ---- fused BN/ReLU + pooling + MLP head ----
  pool_mlp_k<<<G, 256, 0, stream>>>(bufA, batch, bnstats, gammas + (size_t)(L - 1) * F,
                                    betas + (size_t)(L - 1) * F, w1, b1, w2, b2, out, N, invN);
}

// Round 9
// 699.601 us; speedup vs baseline: 1.4252x; 1.0953x over previous
//
#include <hip/hip_runtime.h>
#include <hip/hip_fp16.h>

// GCN forward: deg/dinv -> CSR build (bucketed 2-pass partition) ->
// 3x [MFMA fp16 GEMM (BN/ReLU fused staging, dinv prescale, fp16 table out)
//     -> CSR SpMM gather (fp16 table, fp32 accum) -> BN stats] -> pool+MLP tail.

constexpr int F = 128;
constexpr float BN_EPS = 1e-5f;
constexpr int NB1 = 256;   // partition blocks
constexpr int NBKT = 256;  // buckets of 512 node ids (dst >> 9)

typedef _Float16 f16x8 __attribute__((ext_vector_type(8)));
typedef float f32x4 __attribute__((ext_vector_type(4)));

// ---------------- degree histogram over dst ----------------
__global__ void hist_k(const int* __restrict__ dst, int* __restrict__ degi, int E) {
  int stride = gridDim.x * blockDim.x;
  for (int e = blockIdx.x * blockDim.x + threadIdx.x; e < E; e += stride)
    atomicAdd(&degi[dst[e]], 1);
}

// ---------------- scan stage A: per-chunk(1024) sums + dinv ----------------
__global__ __launch_bounds__(256) void scanA_k(const int* __restrict__ degi, int* __restrict__ bsums,
                                               float* __restrict__ dinv, int n) {
  __shared__ int red[256];
  int tid = threadIdx.x;
  int base = blockIdx.x * 1024 + tid * 4;
  int4 v = *(const int4*)(degi + base);  // padded region is zeroed
  if (base + 0 < n) dinv[base + 0] = rsqrtf((float)v.x + 1.0f);
  if (base + 1 < n) dinv[base + 1] = rsqrtf((float)v.y + 1.0f);
  if (base + 2 < n) dinv[base + 2] = rsqrtf((float)v.z + 1.0f);
  if (base + 3 < n) dinv[base + 3] = rsqrtf((float)v.w + 1.0f);
  red[tid] = v.x + v.y + v.z + v.w;
  __syncthreads();
  for (int off = 128; off > 0; off >>= 1) {
    if (tid < off) red[tid] += red[tid + off];
    __syncthreads();
  }
  if (tid == 0) bsums[blockIdx.x] = red[0];
}

// ---------------- scan stage B: exclusive scan of block sums (1 block) ----------------
__global__ void scanB_k(int* __restrict__ bsums, int nb, int* __restrict__ rowptr, int N) {
  __shared__ int sh[1024];
  int tid = threadIdx.x;
  for (int i = tid; i < nb; i += blockDim.x) sh[i] = bsums[i];
  __syncthreads();
  if (tid == 0) {
    int run = 0;
    for (int i = 0; i < nb; ++i) { int t = sh[i]; sh[i] = run; run += t; }
    rowptr[N] = run;  // == E
  }
  __syncthreads();
  for (int i = tid; i < nb; i += blockDim.x) bsums[i] = sh[i];
}

// ---------------- scan stage C: full exclusive scan -> rowptr ----------------
__global__ __launch_bounds__(256) void scanC_k(const int* __restrict__ degi, const int* __restrict__ bsums,
                                               int* __restrict__ rowptr, int n) {
  __shared__ int ts[256];
  int tid = threadIdx.x;
  int base = blockIdx.x * 1024 + tid * 4;
  int4 v = *(const int4*)(degi + base);
  int e0 = v.x, e1 = v.y, e2 = v.z, e3 = v.w;
  int tot = e0 + e1 + e2 + e3;
  ts[tid] = tot;
  __syncthreads();
  for (int off = 1; off < 256; off <<= 1) {
    int add = (tid >= off) ? ts[tid - off] : 0;
    __syncthreads();
    ts[tid] += add;
    __syncthreads();
  }
  int excl = ts[tid] - tot + bsums[blockIdx.x];
  int p0 = excl, p1 = p0 + e0, p2 = p1 + e1, p3 = p2 + e2;
  if (base + 0 < n) rowptr[base + 0] = p0;
  if (base + 1 < n) rowptr[base + 1] = p1;
  if (base + 2 < n) rowptr[base + 2] = p2;
  if (base + 3 < n) rowptr[base + 3] = p3;
}

// ---------------- CSR build K1: per-(block,bucket) histogram ----------------
__global__ __launch_bounds__(256) void part1_k(const int* __restrict__ dst, int* __restrict__ hist, int E) {
  __shared__ int cnt[NBKT];
  int tid = threadIdx.x;
  cnt[tid] = 0;
  __syncthreads();
  int chunk = (E + NB1 - 1) / NB1;
  int s = blockIdx.x * chunk, e = min(s + chunk, E);
  for (int i = s + tid; i < e; i += 256) atomicAdd(&cnt[dst[i] >> 9], 1);
  __syncthreads();
  hist[blockIdx.x * NBKT + tid] = cnt[tid];  // [blk][bkt], coalesced
}

// ---------------- CSR build K2: exclusive scan in (bucket-major, block-minor) order ----
__global__ __launch_bounds__(1024) void part_scan_k(const int* __restrict__ hist, int* __restrict__ base) {
  __shared__ int sh[1024];
  const int t = threadIdx.x;
  const int per = (NBKT * NB1) / 1024;  // 64
  int sum = 0;
  for (int j = 0; j < per; ++j) {
    int i = t * per + j;               // i = b*NB1 + blk
    sum += hist[(i & (NB1 - 1)) * NBKT + (i >> 8)];
  }
  sh[t] = sum;
  __syncthreads();
  for (int off = 1; off < 1024; off <<= 1) {
    int v = (t >= off) ? sh[t - off] : 0;
    __syncthreads();
    sh[t] += v;
    __syncthreads();
  }
  int run = sh[t] - sum;  // exclusive prefix
  for (int j = 0; j < per; ++j) {
    int i = t * per + j;
    int v = hist[(i & (NB1 - 1)) * NBKT + (i >> 8)];
    base[i] = run;  // base laid out i = b*NB1 + blk
    run += v;
  }
}

// ---------------- CSR build K3: partition (src,dst) pairs into buckets ----------------
__global__ __launch_bounds__(256) void part2_k(const int* __restrict__ src, const int* __restrict__ dst,
                                               const int* __restrict__ base, int2* __restrict__ pairbuf, int E) {
  __shared__ int cnt[NBKT];
  __shared__ int baseL[NBKT];
  int tid = threadIdx.x;
  cnt[tid] = 0;
  baseL[tid] = base[tid * NB1 + blockIdx.x];  // base[b][blk] for this blk
  __syncthreads();
  int chunk = (E + NB1 - 1) / NB1;
  int s = blockIdx.x * chunk, e = min(s + chunk, E);
  for (int i = s + tid; i < e; i += 256) {
    int sv = src[i], dv = dst[i];
    int b = dv >> 9;
    int r = atomicAdd(&cnt[b], 1);
    pairbuf[baseL[b] + r] = make_int2(sv, dv);
  }
}

// ---------------- CSR build K4: per-bucket final scatter with LDS cursors ------------
__global__ __launch_bounds__(256) void scat2_k(const int2* __restrict__ pairbuf, const int* __restrict__ base,
                                               const int* __restrict__ rowptr, int* __restrict__ cols,
                                               int N, int E) {
  __shared__ int curL[512];
  const int b = blockIdx.x;
  const int tid = threadIdx.x;
  const int n0 = b << 9;
  for (int i = tid; i < 512; i += 256) {
    int node = n0 + i;
    curL[i] = (node < N) ? rowptr[node] : 0;
  }
  __syncthreads();
  int lo = base[b * NB1];
  int hi = (b == NBKT - 1) ? E : base[(b + 1) * NB1];
  for (int t = lo + tid; t < hi; t += 256) {
    int2 pr = pairbuf[t];
    int pos = atomicAdd(&curL[pr.y - n0], 1);
    cols[pos] = pr.x;
  }
}

// ---------------- W transpose + fp16 convert: Wt[l][c][k] = fp16(W[l][k][c]) ----------
__global__ __launch_bounds__(128) void wprep_k(const float* __restrict__ W, __half* __restrict__ Wt) {
  const int b = blockIdx.x;        // b = l*128 + c
  const int k = threadIdx.x;       // 128
  const int l = b >> 7, c = b & 127;
  Wt[(size_t)b * 128 + k] = __float2half(W[(size_t)l * 16384 + k * 128 + c]);
}

// ---------------- BN coefficient prep: scsh[0:128]=scale, [128:256]=shift -------------
__global__ void bnprep_k(const float* __restrict__ stats, const float* __restrict__ gamma,
                         const float* __restrict__ beta, float* __restrict__ scsh,
                         int first, float inv_n) {
  int c = threadIdx.x;  // 128
  if (first) { scsh[c] = 1.f; scsh[128 + c] = 0.f; return; }
  float mu = stats[c] * inv_n;
  float var = stats[128 + c] * inv_n - mu * mu;
  float sc = gamma[c] * rsqrtf(var + BN_EPS);
  scsh[c] = sc;
  scsh[128 + c] = beta[c] - mu * sc;
}

// ---------------- MFMA fp16 GEMM: Ch = fp16( dinv .* (bnrelu(A) @ W) ) ---------------
// Block: 256 thr (4 waves), tile 64 rows x 128 cols, K=128.
// A staged as fp16 in XOR-swizzled LDS (16KB); B-frags read from global Wt (L2-hot).
// mfma_f32_16x16x32_f16 layout: A row=lane&15,k=(lane>>4)*8+i; B col=lane&15, same k;
// D row=(lane>>4)*4+reg, col=lane&15.
__global__ __launch_bounds__(256) void gemm_mfma_k(
    const float* __restrict__ A, const __half* __restrict__ Wt,
    __half* __restrict__ Ch, const float* __restrict__ scsh,
    const float* __restrict__ dinv, int n, int dorelu) {
  __shared__ char Al[64 * 256];  // 64 rows x 128 fp16 (256B/row), byte ^= (row&7)<<4
  const int tid = threadIdx.x;
  const int r0 = blockIdx.x * 64;

  // ---- staging: BN/ReLU + fp32->fp16 + swizzled LDS store ----
  {
    const int row = tid & 63;
    const int cb = tid >> 6;        // 32-col chunk per thread
    const int r = r0 + row;
    const int c0 = cb * 32;
    float4 va[8];
    if (r < n) {
      const float* ap = A + (size_t)r * F + c0;
#pragma unroll
      for (int j = 0; j < 8; ++j) va[j] = *(const float4*)(ap + j * 4);
    } else {
#pragma unroll
      for (int j = 0; j < 8; ++j) va[j] = make_float4(0.f, 0.f, 0.f, 0.f);
    }
    union { __half2 h2[16]; int4 q[4]; } u;
#pragma unroll
    for (int j = 0; j < 8; ++j) {
      float4 sc = *(const float4*)(scsh + c0 + j * 4);
      float4 sh = *(const float4*)(scsh + 128 + c0 + j * 4);
      float x0 = fmaf(va[j].x, sc.x, sh.x);
      float x1 = fmaf(va[j].y, sc.y, sh.y);
      float x2 = fmaf(va[j].z, sc.z, sh.z);
      float x3 = fmaf(va[j].w, sc.w, sh.w);
      if (dorelu) {
        x0 = fmaxf(x0, 0.f); x1 = fmaxf(x1, 0.f);
        x2 = fmaxf(x2, 0.f); x3 = fmaxf(x3, 0.f);
      }
      u.h2[2 * j]     = __floats2half2_rn(x0, x1);
      u.h2[2 * j + 1] = __floats2half2_rn(x2, x3);
    }
    const int rowb = row * 256;
    const int swz = (row & 7) << 4;
#pragma unroll
    for (int j = 0; j < 4; ++j) {
      int off = (rowb + cb * 64 + j * 16) ^ swz;
      *(int4*)(Al + off) = u.q[j];
    }
  }
  __syncthreads();

  // ---- compute: wave w -> rows w*16..+16, 8 col-tiles, 4 k-chunks ----
  const int w = tid >> 6, l = tid & 63;
  const int arow = w * 16 + (l & 15);
  const int kg = l >> 4;
  f16x8 af[4];
  {
    const int swz = (arow & 7) << 4;
    const int base = arow * 256 + kg * 16;
#pragma unroll
    for (int kc = 0; kc < 4; ++kc)
      af[kc] = *(const f16x8*)(Al + ((base + kc * 64) ^ swz));
  }
  const int orow = r0 + w * 16 + kg * 4;  // this lane's 4 output rows
  float4 dvv = *(const float4*)(dinv + orow);  // dinv carve padded to 256B: safe
  float dvr[4] = {dvv.x, dvv.y, dvv.z, dvv.w};

#pragma unroll
  for (int t = 0; t < 8; ++t) {
    const __half* wp = Wt + ((size_t)(t * 16 + (l & 15)) * 128 + kg * 8);
    f32x4 acc = {0.f, 0.f, 0.f, 0.f};
#pragma unroll
    for (int kc = 0; kc < 4; ++kc) {
      f16x8 bf = *(const f16x8*)(wp + kc * 32);
      acc = __builtin_amdgcn_mfma_f32_16x16x32_f16(af[kc], bf, acc, 0, 0, 0);
    }
    const int ccol = t * 16 + (l & 15);
#pragma unroll
    for (int rr = 0; rr < 4; ++rr) {
      int r = orow + rr;
      if (r < n) Ch[(size_t)r * F + ccol] = __float2half(acc[rr] * dvr[rr]);
    }
  }
}

// ---------------- CSR SpMM aggregate: one wave per dst row, fp16 gather --------------
__global__ __launch_bounds__(256) void spmm_k(const __half* __restrict__ hw, const int* __restrict__ rowptr,
                                              const int* __restrict__ cols, const float* __restrict__ dinv,
                                              const float* __restrict__ bias, float* __restrict__ out, int n) {
  int wid = (blockIdx.x * 256 + threadIdx.x) >> 6;
  int lane = threadIdx.x & 63;
  if (wid >= n) return;
  const __half2* hw2 = (const __half2*)hw;
  float2 vf = __half22float2(hw2[(size_t)wid * 64 + lane]);
  float ax = vf.x, ay = vf.y;  // self-loop term
  int j = rowptr[wid];
  const int e = rowptr[wid + 1];
  for (; j + 8 <= e; j += 8) {
    int c0 = cols[j + 0], c1 = cols[j + 1], c2 = cols[j + 2], c3 = cols[j + 3];
    int c4 = cols[j + 4], c5 = cols[j + 5], c6 = cols[j + 6], c7 = cols[j + 7];
    float2 v0 = __half22float2(hw2[(size_t)c0 * 64 + lane]);
    float2 v1 = __half22float2(hw2[(size_t)c1 * 64 + lane]);
    float2 v2 = __half22float2(hw2[(size_t)c2 * 64 + lane]);
    float2 v3 = __half22float2(hw2[(size_t)c3 * 64 + lane]);
    float2 v4 = __half22float2(hw2[(size_t)c4 * 64 + lane]);
    float2 v5 = __half22float2(hw2[(size_t)c5 * 64 + lane]);
    float2 v6 = __half22float2(hw2[(size_t)c6 * 64 + lane]);
    float2 v7 = __half22float2(hw2[(size_t)c7 * 64 + lane]);
    ax += ((v0.x + v1.x) + (v2.x + v3.x)) + ((v4.x + v5.x) + (v6.x + v7.x));
    ay += ((v0.y + v1.y) + (v2.y + v3.y)) + ((v4.y + v5.y) + (v6.y + v7.y));
  }
  if (j + 4 <= e) {
    int c0 = cols[j + 0], c1 = cols[j + 1], c2 = cols[j + 2], c3 = cols[j + 3];
    float2 v0 = __half22float2(hw2[(size_t)c0 * 64 + lane]);
    float2 v1 = __half22float2(hw2[(size_t)c1 * 64 + lane]);
    float2 v2 = __half22float2(hw2[(size_t)c2 * 64 + lane]);
    float2 v3 = __half22float2(hw2[(size_t)c3 * 64 + lane]);
    ax += (v0.x + v1.x) + (v2.x + v3.x);
    ay += (v0.y + v1.y) + (v2.y + v3.y);
    j += 4;
  }
  for (; j < e; ++j) {
    float2 vv = __half22float2(hw2[(size_t)cols[j] * 64 + lane]);
    ax += vv.x;
    ay += vv.y;
  }
  float di = dinv[wid];
  float2 b = ((const float2*)bias)[lane];
  float2 o;
  o.x = fmaf(di, ax, b.x);
  o.y = fmaf(di, ay, b.y);
  ((float2*)out)[(size_t)wid * 64 + lane] = o;
}

// ---------------- BN statistics: sum & sumsq per feature ----------------
__global__ __launch_bounds__(256) void stats_k(const float* __restrict__ h, float* __restrict__ stats, int n) {
  __shared__ float s1[256], s2[256];
  int tid = threadIdx.x;
  int c = tid & 127, half = tid >> 7;
  float a = 0.f, b = 0.f;
  for (int r = blockIdx.x * 2 + half; r < n; r += gridDim.x * 2) {
    float v = h[(size_t)r * F + c];
    a += v;
    b += v * v;
  }
  s1[tid] = a; s2[tid] = b;
  __syncthreads();
  if (tid < 128) {
    atomicAdd(&stats[c], s1[tid] + s1[tid + 128]);
    atomicAdd(&stats[F + c], s2[tid] + s2[tid + 128]);
  }
}

// ---------------- fused BN/ReLU + segment mean/max pool + MLP head ----------------
__global__ __launch_bounds__(256) void pool_mlp_k(
    const float* __restrict__ h, const int* __restrict__ batch,
    const float* __restrict__ stats, const float* __restrict__ gamma,
    const float* __restrict__ beta, const float* __restrict__ w1,
    const float* __restrict__ b1, const float* __restrict__ w2,
    const float* __restrict__ b2, float* __restrict__ out,
    int n, float inv_n) {
  __shared__ float psum[4][128];
  __shared__ float pmax[4][128];
  __shared__ float zsh[256];
  __shared__ float part[4][64];
  const int g = blockIdx.x;
  const int tid = threadIdx.x;
  const int wave = tid >> 6, lane = tid & 63;

  int lo = 0, hi = n;
  while (lo < hi) { int m = (lo + hi) >> 1; if (batch[m] < g) lo = m + 1; else hi = m; }
  const int s = lo;
  hi = n;
  while (lo < hi) { int m = (lo + hi) >> 1; if (batch[m] < g + 1) lo = m + 1; else hi = m; }
  const int e = lo;

  const int c = lane * 2;
  float2 st = *(const float2*)(stats + c);
  float2 sq = *(const float2*)(stats + F + c);
  float2 ga = *(const float2*)(gamma + c);
  float2 be = *(const float2*)(beta + c);
  float mu0 = st.x * inv_n, mu1 = st.y * inv_n;
  float sc0 = ga.x * rsqrtf(sq.x * inv_n - mu0 * mu0 + BN_EPS);
  float sc1 = ga.y * rsqrtf(sq.y * inv_n - mu1 * mu1 + BN_EPS);
  float sh0 = be.x - mu0 * sc0;
  float sh1 = be.y - mu1 * sc1;

  float sum0 = 0.f, sum1 = 0.f, mx0 = 0.f, mx1 = 0.f;  // post-ReLU >= 0
#pragma unroll 2
  for (int r = s + wave; r < e; r += 4) {
    float2 v = *(const float2*)(h + (size_t)r * F + c);
    float h0 = fmaxf(fmaf(v.x, sc0, sh0), 0.f);
    float h1 = fmaxf(fmaf(v.y, sc1, sh1), 0.f);
    sum0 += h0; sum1 += h1;
    mx0 = fmaxf(mx0, h0); mx1 = fmaxf(mx1, h1);
  }
  psum[wave][c] = sum0; psum[wave][c + 1] = sum1;
  pmax[wave][c] = mx0;  pmax[wave][c + 1] = mx1;
  __syncthreads();

  if (tid < 128) {
    float sm = psum[0][tid] + psum[1][tid] + psum[2][tid] + psum[3][tid];
    float mx = fmaxf(fmaxf(pmax[0][tid], pmax[1][tid]), fmaxf(pmax[2][tid], pmax[3][tid]));
    float ic = (e > s) ? 1.0f / (float)(e - s) : 0.f;
    zsh[tid] = sm * ic;
    zsh[128 + tid] = mx;
  }
  __syncthreads();

  {
    const int j = lane, q = wave;
    float acc = 0.f;
    const float* wq = w1 + (size_t)q * 64 * 64 + j;
#pragma unroll 8
    for (int i = 0; i < 64; ++i) acc = fmaf(zsh[q * 64 + i], wq[(size_t)i * 64], acc);
    part[q][j] = acc;
  }
  __syncthreads();

  if (tid < 64) {
    float hid = part[0][tid] + part[1][tid] + part[2][tid] + part[3][tid] + b1[tid];
    hid = fmaxf(hid, 0.f) * w2[tid];
    for (int off = 32; off > 0; off >>= 1) hid += __shfl_down(hid, off);
    if (tid == 0) out[g] = hid + b2[0];
  }
}

extern "C" void kernel_launch(void* const* d_in, const int* in_sizes, int n_in,
                              void* d_out, int out_size, void* d_ws, size_t ws_size,
                              hipStream_t stream) {
  const float* x      = (const float*)d_in[0];
  const int*   ei     = (const int*)d_in[1];
  const int*   batch  = (const int*)d_in[2];
  const float* Ws     = (const float*)d_in[3];
  const float* bsv    = (const float*)d_in[4];
  const float* gammas = (const float*)d_in[5];
  const float* betas  = (const float*)d_in[6];
  const float* w1     = (const float*)d_in[7];
  const float* b1     = (const float*)d_in[8];
  const float* w2     = (const float*)d_in[9];
  const float* b2     = (const float*)d_in[10];
  float* out = (float*)d_out;

  const int N = in_sizes[0] / F;          // 100000
  const int E = in_sizes[1] / 2;          // 1600000
  const int G = out_size;                 // 512
  const int L = in_sizes[3] / (F * F);    // 3
  const int* srcp = ei;
  const int* dstp = ei + E;
  const int NB = (N + 1023) / 1024;

  char* p = (char*)d_ws;
  auto carve = [&](size_t bytes) {
    char* r = p;
    p += (bytes + 255) & ~(size_t)255;
    return r;
  };
  int*    degi    = (int*)carve((size_t)NB * 1024 * 4);
  float*  dinv    = (float*)carve((size_t)N * 4);
  int*    rowptr  = (int*)carve(((size_t)N + 1) * 4);
  int*    colsb   = (int*)carve((size_t)E * 4);
  int*    bsums   = (int*)carve(4096);
  int*    hist    = (int*)carve((size_t)NB1 * NBKT * 4);
  int*    pbase   = (int*)carve((size_t)NB1 * NBKT * 4);
  int2*   pairbuf = (int2*)carve((size_t)E * 8);
  float*  bnstats = (float*)carve(2 * F * 4);
  float*  scsh    = (float*)carve(2 * F * 4);
  __half* wth     = (__half*)carve((size_t)L * F * F * 2);
  __half* hwh     = (__half*)carve((size_t)N * F * 2);
  float*  bufA    = (float*)carve((size_t)N * F * 4);
  (void)ws_size; (void)n_in;

  // ---- degrees + bucketed CSR build + W fp16 transpose (every call) ----
  hipMemsetAsync(degi, 0, (size_t)NB * 1024 * 4, stream);
  hist_k<<<2048, 256, 0, stream>>>(dstp, degi, E);
  scanA_k<<<NB, 256, 0, stream>>>(degi, bsums, dinv, N);
  scanB_k<<<1, 1024, 0, stream>>>(bsums, NB, rowptr, N);
  scanC_k<<<NB, 256, 0, stream>>>(degi, bsums, rowptr, N);
  part1_k<<<NB1, 256, 0, stream>>>(dstp, hist, E);
  part_scan_k<<<1, 1024, 0, stream>>>(hist, pbase);
  part2_k<<<NB1, 256, 0, stream>>>(srcp, dstp, pbase, pairbuf, E);
  scat2_k<<<NBKT, 256, 0, stream>>>(pairbuf, pbase, rowptr, colsb, N, E);
  wprep_k<<<L * F, 128, 0, stream>>>(Ws, wth);

  // ---- 3 GCN layers ----
  const float invN = 1.0f / (float)N;
  const int gblocks = (N + 63) / 64;
  for (int l = 0; l < L; ++l) {
    const float* hin = (l == 0) ? x : bufA;
    const float* ga  = (l == 0) ? gammas : gammas + (size_t)(l - 1) * F;
    const float* be  = (l == 0) ? betas : betas + (size_t)(l - 1) * F;
    bnprep_k<<<1, 128, 0, stream>>>(bnstats, ga, be, scsh, (l == 0) ? 1 : 0, invN);
    gemm_mfma_k<<<gblocks, 256, 0, stream>>>(hin, wth + (size_t)l * F * F, hwh, scsh, dinv, N,
                                             (l == 0) ? 0 : 1);
    hipMemsetAsync(bnstats, 0, 2 * F * 4, stream);
    spmm_k<<<(N * 64 + 255) / 256, 256, 0, stream>>>(hwh, rowptr, colsb, dinv,
                                                     bsv + (size_t)l * F, bufA, N);
    stats_k<<<512, 256, 0, stream>>>(bufA, bnstats, N);
  }

  // ---- fused BN/ReLU + pooling + MLP head ----
  pool_mlp_k<<<G, 256, 0, stream>>>(bufA, batch, bnstats, gammas + (size_t)(L - 1) * F,
                                    betas + (size_t)(L - 1) * F, w1, b1, w2, b2, out, N, invN);
}